// Round 1
// baseline (1090.938 us; speedup 1.0000x reference)
//
#include <hip/hip_runtime.h>

// YOLO decode: x[B,255,S,S] -> out[B, S*S*3, 85] with
//   xy  = (sigmoid(t[0:2])*1.05 - 0.025 + grid) * stride
//   wh  = exp(t[2:4]) * anchor
//   rest= sigmoid(t[4:85])
// Pure transpose + elementwise: memory-bound. LDS-staged transpose so both
// global read (channel rows, contiguous hw) and global write (contiguous
// 255*T span) are coalesced.

#define TILE 32  // hw positions per block

__device__ __forceinline__ float sigmoidf_(float v) {
    return 1.0f / (1.0f + expf(-v));
}

__global__ __launch_bounds__(256) void yolo_decode_kernel(
    const float* __restrict__ in, float* __restrict__ out,
    int S, int S2, int seg_off, float stride,
    float aw0, float ah0, float aw1, float ah1, float aw2, float ah2)
{
    // +1 pad: load writes lds[ch][p] (row-contig, conflict-free);
    // store reads lds[ch][p] with ch varying per lane -> stride 33 -> conflict-free.
    __shared__ float lds[255][TILE + 1];

    const int b   = blockIdx.y;
    const int hw0 = blockIdx.x * TILE;
    const int tid = threadIdx.x;
    const int nvalid = min(TILE, S2 - hw0);

    const float* __restrict__ src = in + (size_t)b * 255 * (size_t)S2;

    // ---- load: 255 channel rows x TILE contiguous hw ----
    for (int idx = tid; idx < 255 * TILE; idx += 256) {
        int ch = idx >> 5;           // idx / TILE
        int p  = idx & (TILE - 1);   // idx % TILE
        if (p < nvalid) lds[ch][p] = src[(size_t)ch * S2 + hw0 + p];
    }
    __syncthreads();

    // ---- decode + store: contiguous span of nvalid*255 floats ----
    // out offset for (hw0+p, a, c) = base + p*255 + a*85 + c = base + j
    float* __restrict__ dst =
        out + ((size_t)b * 22743 + (size_t)seg_off) * 85 + (size_t)hw0 * 255;

    const int jmax = nvalid * 255;   // valid j are exactly [0, nvalid*255)
    for (int j = tid; j < jmax; j += 256) {
        unsigned int uj = (unsigned int)j;
        unsigned int p  = uj / 255u;
        unsigned int ch = uj - p * 255u;
        float v = lds[ch][p];
        unsigned int a = ch / 85u;       // 0..2
        unsigned int c = ch - a * 85u;

        float r;
        if (c == 0u) {
            unsigned int hw = hw0 + p;
            unsigned int gx = hw % (unsigned int)S;
            r = (sigmoidf_(v) * 1.05f - 0.025f + (float)gx) * stride;
        } else if (c == 1u) {
            unsigned int hw = hw0 + p;
            unsigned int gy = hw / (unsigned int)S;
            r = (sigmoidf_(v) * 1.05f - 0.025f + (float)gy) * stride;
        } else if (c == 2u) {
            float aw = (a == 0u) ? aw0 : ((a == 1u) ? aw1 : aw2);
            r = expf(v) * aw;
        } else if (c == 3u) {
            float ah = (a == 0u) ? ah0 : ((a == 1u) ? ah1 : ah2);
            r = expf(v) * ah;
        } else {
            r = sigmoidf_(v);
        }
        dst[j] = r;
    }
}

extern "C" void kernel_launch(void* const* d_in, const int* in_sizes, int n_in,
                              void* d_out, int out_size, void* d_ws, size_t ws_size,
                              hipStream_t stream) {
    const float* x0 = (const float*)d_in[0];  // [64,255,76,76]
    const float* x1 = (const float*)d_in[1];  // [64,255,38,38]
    const float* x2 = (const float*)d_in[2];  // [64,255,19,19]
    float* out = (float*)d_out;               // [64, 22743, 85]

    dim3 block(256);

    // scale 0: S=76, stride 8, anchors (28,28)(46,45)(64,66), seg_off 0
    yolo_decode_kernel<<<dim3((5776 + TILE - 1) / TILE, 64), block, 0, stream>>>(
        x0, out, 76, 5776, 0, 8.0f,
        28.0f, 28.0f, 46.0f, 45.0f, 64.0f, 66.0f);

    // scale 1: S=38, stride 16, anchors (102,74)(78,115)(132,113), seg_off 17328
    yolo_decode_kernel<<<dim3((1444 + TILE - 1) / TILE, 64), block, 0, stream>>>(
        x1, out, 38, 1444, 17328, 16.0f,
        102.0f, 74.0f, 78.0f, 115.0f, 132.0f, 113.0f);

    // scale 2: S=19, stride 32, anchors (149,163)(174,268)(257,176), seg_off 21660
    yolo_decode_kernel<<<dim3((361 + TILE - 1) / TILE, 64), block, 0, stream>>>(
        x2, out, 19, 361, 21660, 32.0f,
        149.0f, 163.0f, 174.0f, 268.0f, 257.0f, 176.0f);
}

// Round 2
// 790.639 us; speedup vs baseline: 1.3798x; 1.3798x over previous
//
#include <hip/hip_runtime.h>

// YOLO decode, fused across the 3 scales:
//   x[B,255,S,S] -> out[B, S*S*3, 85]
//   xy  = sigmoid(v)*(1.05*stride) + (g - 0.025)*stride
//   wh  = exp(v)*anchor
//   rest= sigmoid(v)
// Memory-bound transpose; store phase arranged so each thread owns ONE
// channel (per-thread decode constants hoisted out of the loop; no per-
// element div/mod, no branches), native exp/rcp for the transcendentals.

#define TILE 32  // hw positions per block

__global__ __launch_bounds__(256) void yolo_fused_kernel(
    const float* __restrict__ x0, const float* __restrict__ x1,
    const float* __restrict__ x2, float* __restrict__ out)
{
    // stride-33 rows: conflict-free on both the (row-contig) writes and the
    // (column, lane=ch) reads: bank = (33*ch+p)%32 = (ch+p)%32 -> 2-way max.
    __shared__ float lds[255][TILE + 1];
    __shared__ float gadd[2][TILE];  // (gx-0.025)*stride, (gy-0.025)*stride per p

    const int t   = blockIdx.x;
    const int b   = blockIdx.y;
    const int tid = threadIdx.x;

    // ---- per-scale parameters (block-uniform selection) ----
    const float* src; int S, S2, seg_off, tile; float stride;
    float aw0, ah0, aw1, ah1, aw2, ah2; bool vec;
    if (t < 181) {
        src = x0; S = 76; S2 = 5776; seg_off = 0;     stride = 8.0f;  tile = t;
        aw0 = 28.f;  ah0 = 28.f;  aw1 = 46.f;  ah1 = 45.f;  aw2 = 64.f;  ah2 = 66.f;
        vec = true;
    } else if (t < 227) {
        src = x1; S = 38; S2 = 1444; seg_off = 17328; stride = 16.0f; tile = t - 181;
        aw0 = 102.f; ah0 = 74.f;  aw1 = 78.f;  ah1 = 115.f; aw2 = 132.f; ah2 = 113.f;
        vec = true;
    } else {
        src = x2; S = 19; S2 = 361;  seg_off = 21660; stride = 32.0f; tile = t - 227;
        aw0 = 149.f; ah0 = 163.f; aw1 = 174.f; ah1 = 268.f; aw2 = 257.f; ah2 = 176.f;
        vec = false;
    }

    const int hw0    = tile * TILE;
    const int nvalid = min(TILE, S2 - hw0);
    src += (size_t)b * 255 * (size_t)S2;

    // ---- load: 255 channel rows x TILE contiguous hw (float4 when S2%4==0) ----
    if (vec) {
        const float4* __restrict__ s4 = reinterpret_cast<const float4*>(src + hw0);
        const int rs = S2 >> 2;  // row stride in float4
        for (int idx = tid; idx < 255 * (TILE / 4); idx += 256) {
            int ch = idx >> 3;          // idx / 8
            int q  = idx & 7;           // idx % 8
            int p  = q << 2;
            if (p < nvalid) {
                float4 v = s4[ch * rs + q];
                lds[ch][p]     = v.x;
                lds[ch][p + 1] = v.y;
                lds[ch][p + 2] = v.z;
                lds[ch][p + 3] = v.w;
            }
        }
    } else {
        for (int idx = tid; idx < 255 * TILE; idx += 256) {
            int ch = idx >> 5;
            int p  = idx & (TILE - 1);
            if (p < nvalid) lds[ch][p] = src[ch * S2 + hw0 + p];
        }
    }
    if (tid < TILE) {  // grid-term table (32 threads, once per block)
        int hw = hw0 + tid;
        int gy = hw / S;
        int gx = hw - gy * S;
        gadd[0][tid] = ((float)gx - 0.025f) * stride;
        gadd[1][tid] = ((float)gy - 0.025f) * stride;
    }
    __syncthreads();

    // ---- decode + store: thread t owns channel ch=t; constants hoisted ----
    const int ch = tid;
    if (ch < 255) {
        int a = ch / 85;
        int c = ch - a * 85;
        bool use_exp = (c == 2) | (c == 3);
        float mulA;
        int addsel;  // 0: +gx term, 1: +gy term, 2: none
        if (c == 0)      { mulA = 1.05f * stride; addsel = 0; }
        else if (c == 1) { mulA = 1.05f * stride; addsel = 1; }
        else if (c == 2) { mulA = (a == 0) ? aw0 : (a == 1) ? aw1 : aw2; addsel = 2; }
        else if (c == 3) { mulA = (a == 0) ? ah0 : (a == 1) ? ah1 : ah2; addsel = 2; }
        else             { mulA = 1.0f; addsel = 2; }

        float* __restrict__ dst =
            out + ((size_t)b * 22743 + (size_t)seg_off) * 85 + (size_t)hw0 * 255 + ch;

        #pragma unroll 4
        for (int p = 0; p < nvalid; ++p) {
            float v = lds[ch][p];
            float e = __expf(use_exp ? v : -v);                       // v_exp_f32
            float s = use_exp ? e : __builtin_amdgcn_rcpf(1.0f + e);  // v_rcp_f32
            float add = (addsel == 0) ? gadd[0][p]
                      : (addsel == 1) ? gadd[1][p] : 0.0f;
            dst[(size_t)p * 255] = s * mulA + add;
        }
    }
}

extern "C" void kernel_launch(void* const* d_in, const int* in_sizes, int n_in,
                              void* d_out, int out_size, void* d_ws, size_t ws_size,
                              hipStream_t stream) {
    const float* x0 = (const float*)d_in[0];  // [64,255,76,76]
    const float* x1 = (const float*)d_in[1];  // [64,255,38,38]
    const float* x2 = (const float*)d_in[2];  // [64,255,19,19]
    float* out = (float*)d_out;               // [64, 22743, 85]

    // tiles: ceil(5776/32)=181, ceil(1444/32)=46, ceil(361/32)=12 -> 239
    yolo_fused_kernel<<<dim3(239, 64), dim3(256), 0, stream>>>(x0, x1, x2, out);
}

// Round 3
// 782.565 us; speedup vs baseline: 1.3941x; 1.0103x over previous
//
#include <hip/hip_runtime.h>

// YOLO decode, fused across the 3 scales:
//   x[B,255,S,S] -> out[B, S*S*3, 85]
//   xy  = sigmoid(v)*(1.05*stride) + (g - 0.025)*stride
//   wh  = exp(v)*anchor
//   rest= sigmoid(v)
// Memory-bound transpose via padded LDS. 512-thread blocks so the 33.8 KB
// LDS tile still fits 4 blocks/CU but occupancy hits 32 waves/CU (100%),
// doubling latency-hiding TLP vs the 256-thread version.

#define TILE 32  // hw positions per block

__global__ __launch_bounds__(512) void yolo_fused_kernel(
    const float* __restrict__ x0, const float* __restrict__ x1,
    const float* __restrict__ x2, float* __restrict__ out)
{
    // stride-33 rows: bank = (33*ch+p)%32 = (ch+p)%32 -> conflict-free on the
    // row-contig writes and <=2-way on the lane=ch column reads.
    __shared__ float lds[255][TILE + 1];
    __shared__ float gadd[2][TILE];  // (gx-0.025)*stride, (gy-0.025)*stride

    const int t   = blockIdx.x;
    const int b   = blockIdx.y;
    const int tid = threadIdx.x;

    // ---- per-scale parameters (block-uniform selection) ----
    const float* src; int S, S2, seg_off, tile; float stride;
    float aw0, ah0, aw1, ah1, aw2, ah2; bool vec;
    if (t < 181) {
        src = x0; S = 76; S2 = 5776; seg_off = 0;     stride = 8.0f;  tile = t;
        aw0 = 28.f;  ah0 = 28.f;  aw1 = 46.f;  ah1 = 45.f;  aw2 = 64.f;  ah2 = 66.f;
        vec = true;
    } else if (t < 227) {
        src = x1; S = 38; S2 = 1444; seg_off = 17328; stride = 16.0f; tile = t - 181;
        aw0 = 102.f; ah0 = 74.f;  aw1 = 78.f;  ah1 = 115.f; aw2 = 132.f; ah2 = 113.f;
        vec = true;
    } else {
        src = x2; S = 19; S2 = 361;  seg_off = 21660; stride = 32.0f; tile = t - 227;
        aw0 = 149.f; ah0 = 163.f; aw1 = 174.f; ah1 = 268.f; aw2 = 257.f; ah2 = 176.f;
        vec = false;
    }

    const int hw0    = tile * TILE;
    const int nvalid = min(TILE, S2 - hw0);
    src += (size_t)b * 255 * (size_t)S2;

    // ---- load: 255 channel rows x TILE contiguous hw (float4 when S2%4==0) ----
    if (vec) {
        const float4* __restrict__ s4 = reinterpret_cast<const float4*>(src + hw0);
        const int rs = S2 >> 2;  // row stride in float4
        for (int idx = tid; idx < 255 * (TILE / 4); idx += 512) {
            int ch = idx >> 3;          // idx / 8
            int q  = idx & 7;           // idx % 8
            int p  = q << 2;
            if (p < nvalid) {
                float4 v = s4[ch * rs + q];
                lds[ch][p]     = v.x;
                lds[ch][p + 1] = v.y;
                lds[ch][p + 2] = v.z;
                lds[ch][p + 3] = v.w;
            }
        }
    } else {
        for (int idx = tid; idx < 255 * TILE; idx += 512) {
            int ch = idx >> 5;
            int p  = idx & (TILE - 1);
            if (p < nvalid) lds[ch][p] = src[ch * S2 + hw0 + p];
        }
    }
    if (tid < TILE) {  // grid-term table (32 threads, once per block)
        int hw = hw0 + tid;
        int gy = hw / S;
        int gx = hw - gy * S;
        gadd[0][tid] = ((float)gx - 0.025f) * stride;
        gadd[1][tid] = ((float)gy - 0.025f) * stride;
    }
    __syncthreads();

    // ---- decode + store: thread = (channel, p-half); all 512 threads busy ----
    const int ch   = tid & 255;   // 0..255 (255 invalid)
    const int half = tid >> 8;    // 0..1 -> p range [16*half, 16*half+16)
    if (ch < 255) {
        int a = ch / 85;
        int c = ch - a * 85;
        bool use_exp = (c == 2) | (c == 3);
        float mulA;
        int addsel;  // 0: +gx term, 1: +gy term, 2: none
        if (c == 0)      { mulA = 1.05f * stride; addsel = 0; }
        else if (c == 1) { mulA = 1.05f * stride; addsel = 1; }
        else if (c == 2) { mulA = (a == 0) ? aw0 : (a == 1) ? aw1 : aw2; addsel = 2; }
        else if (c == 3) { mulA = (a == 0) ? ah0 : (a == 1) ? ah1 : ah2; addsel = 2; }
        else             { mulA = 1.0f; addsel = 2; }

        float* __restrict__ dst =
            out + ((size_t)b * 22743 + (size_t)seg_off) * 85 + (size_t)hw0 * 255 + ch;

        const int p0 = half * 16;
        const int p1 = min(p0 + 16, nvalid);
        #pragma unroll 4
        for (int p = p0; p < p1; ++p) {
            float v = lds[ch][p];
            float e = __expf(use_exp ? v : -v);                       // v_exp_f32
            float s = use_exp ? e : __builtin_amdgcn_rcpf(1.0f + e);  // v_rcp_f32
            float add = (addsel == 0) ? gadd[0][p]
                      : (addsel == 1) ? gadd[1][p] : 0.0f;
            dst[(size_t)p * 255] = s * mulA + add;
        }
    }
}

extern "C" void kernel_launch(void* const* d_in, const int* in_sizes, int n_in,
                              void* d_out, int out_size, void* d_ws, size_t ws_size,
                              hipStream_t stream) {
    const float* x0 = (const float*)d_in[0];  // [64,255,76,76]
    const float* x1 = (const float*)d_in[1];  // [64,255,38,38]
    const float* x2 = (const float*)d_in[2];  // [64,255,19,19]
    float* out = (float*)d_out;               // [64, 22743, 85]

    // tiles: ceil(5776/32)=181, ceil(1444/32)=46, ceil(361/32)=12 -> 239
    yolo_fused_kernel<<<dim3(239, 64), dim3(512), 0, stream>>>(x0, x1, x2, out);
}